// Round 10
// baseline (236.322 us; speedup 1.0000x reference)
//
#include <hip/hip_runtime.h>

typedef _Float16 f16;
typedef _Float16 f16x8 __attribute__((ext_vector_type(8)));
typedef float f32x4 __attribute__((ext_vector_type(4)));

// async global->LDS, 16B per lane; LDS dest = wave-uniform base + lane*16
#define GLD16(g, l) __builtin_amdgcn_global_load_lds( \
    (const __attribute__((address_space(1))) void*)(g), \
    (__attribute__((address_space(3))) void*)(l), 16, 0, 0)

// ---------------------------------------------------------------------------
// Generic f16 MFMA GEMM, BK=64: C[m][n] = sum_k A[m][k]*B[n][k] (+bias)
// A: [M][K] f16 row-major, B: [N][K] f16 row-major (B^T layout).
// MODE: 0 none, 1 bias[col], 2 bias[row], 3 split-QK (col<768 -> C else C2).
// Two-barrier single-buffer K-loop — the R5 champion structure.
// SESSION EVIDENCE (R1-R9):
//  - single-barrier dbuf w/o fences RACES under graph replay (R3); fence-
//    hardened dbuf (R9) is CORRECT but -7us: LDS doubling costs occupancy,
//    and TLP > same-wave ILP in this structure (matches m99/m131-m141).
//  - shapes: scores 128x256 beats 128x128 by ~10us; PV/out variants +-3us.
//  - XOR swizzle (slot s of row r holds chunk s^(r&7)): SQ_LDS_BANK_CONFLICT=0.
//  - epilogues must be row-major/coalesced (R6: transposed epi +24MB writes).
// ---------------------------------------------------------------------------
template <typename OutT, int BM, int BN, int MODE, int MINW>
__global__ __launch_bounds__(256, MINW)
void gemm_kernel(const f16* __restrict__ A, long sA,
                 const f16* __restrict__ B, long sB,
                 void* __restrict__ Cv, long sC,
                 void* __restrict__ C2v,
                 const float* __restrict__ bias,
                 const float* __restrict__ bias2,
                 int N, int K)
{
    constexpr int FM = BM / 32;   // A-frags per wave
    constexpr int FN = BN / 32;
    constexpr int IA = BM / 32;   // staging issues per wave (8 rows each)
    constexpr int IB = BN / 32;

    OutT* C  = (OutT*)Cv;
    OutT* C2 = (OutT*)C2v;
    const int tid  = threadIdx.x;
    const int wave = tid >> 6;
    const int lane = tid & 63;
    const int bz   = blockIdx.z;
    A += (long)bz * sA;
    B += (long)bz * sB;
    C += (long)bz * sC;
    const long bm = (long)blockIdx.x * BM;
    const long bn = (long)blockIdx.y * BN;

    __shared__ f16 sAt[BM * 64];
    __shared__ f16 sBt[BN * 64];

    // staging lane map: row = lane>>3, slot = lane&7, source chunk slot^row
    const int srow = lane >> 3;
    const int gch  = ((lane & 7) ^ srow) * 8;

    const f16* gAb = A + (bm + wave * (BM / 4) + srow) * (long)K + gch;
    const f16* gBb = B + (bn + wave * (BN / 4) + srow) * (long)K + gch;

    const int wm = (wave >> 1) * (BM / 2);
    const int wn = (wave & 1) * (BN / 2);
    const int lr = lane & 15;
    const int qd = lane >> 4;
    // reader swizzle per k-group h: slot = (h*4+qd) ^ (lr&7)
    const int swz0 = ((0 * 4 + qd) ^ (lr & 7)) * 8;
    const int swz1 = ((1 * 4 + qd) ^ (lr & 7)) * 8;

    f32x4 acc[FM][FN] = {};

    for (int k0 = 0; k0 < K; k0 += 64) {
        #pragma unroll
        for (int i = 0; i < IA; ++i)
            GLD16(gAb + k0 + (long)i * 8 * K, &sAt[(wave * (BM / 4) + i * 8) * 64]);
        #pragma unroll
        for (int i = 0; i < IB; ++i)
            GLD16(gBb + k0 + (long)i * 8 * K, &sBt[(wave * (BN / 4) + i * 8) * 64]);
        __syncthreads();

        #pragma unroll
        for (int h = 0; h < 2; ++h) {
            const int swz = h ? swz1 : swz0;
            f16x8 af[FM], bf[FN];
            #pragma unroll
            for (int t = 0; t < FM; ++t)
                af[t] = *(const f16x8*)&sAt[(wm + t * 16 + lr) * 64 + swz];
            #pragma unroll
            for (int t = 0; t < FN; ++t)
                bf[t] = *(const f16x8*)&sBt[(wn + t * 16 + lr) * 64 + swz];
            #pragma unroll
            for (int tm = 0; tm < FM; ++tm)
                #pragma unroll
                for (int tn = 0; tn < FN; ++tn)
                    acc[tm][tn] = __builtin_amdgcn_mfma_f32_16x16x32_f16(
                        af[tm], bf[tn], acc[tm][tn], 0, 0, 0);
        }
        __syncthreads();
    }

    // epilogue: C/D layout col = lane&15, row = (lane>>4)*4 + reg
    #pragma unroll
    for (int tn = 0; tn < FN; ++tn) {
        const long col = bn + wn + tn * 16 + lr;
        OutT* dst = C;
        long cc = col, stride = N;
        float bc = 0.f;
        if (MODE == 1) bc = bias[col];
        if (MODE == 3) {
            stride = 768;
            if (col >= 768) { dst = C2; cc = col - 768; bc = bias2[cc]; }
            else            { bc = bias[cc]; }
        }
        #pragma unroll
        for (int tm = 0; tm < FM; ++tm) {
            #pragma unroll
            for (int r = 0; r < 4; ++r) {
                const long row = bm + wm + tm * 16 + qd * 4 + r;
                float v = acc[tm][tn][r] + bc;
                if (MODE == 2) v += bias[row];
                dst[row * stride + cc] = (OutT)v;
            }
        }
    }
}

// ---------------------------------------------------------------------------
// In-place row softmax over f16 scores; ONE ROW PER WAVE, 4 rows/block.
// Pure 64-lane shuffle reduction — no LDS, no __syncthreads.
// Lane i holds row elements [i*32, i*32+32) as 4x f16x8 (fully coalesced).
// fp32 math, unscaled (faithful to reference: no 1/sqrt(d), no mask).
// ---------------------------------------------------------------------------
__global__ __launch_bounds__(256)
void softmax_kernel(f16* __restrict__ S)
{
    const int wave = threadIdx.x >> 6;
    const int lane = threadIdx.x & 63;
    const long row = (long)blockIdx.x * 4 + wave;
    f16* p = S + row * 2048 + lane * 32;

    f16x8 x[4];
    float v[32];
    float m = -3.0e38f;
    #pragma unroll
    for (int c = 0; c < 4; ++c) {
        x[c] = *(const f16x8*)&p[c * 8];
        #pragma unroll
        for (int j = 0; j < 8; ++j) {
            v[c * 8 + j] = (float)x[c][j];
            m = fmaxf(m, v[c * 8 + j]);
        }
    }
    #pragma unroll
    for (int off = 32; off > 0; off >>= 1) m = fmaxf(m, __shfl_xor(m, off));

    float s = 0.f;
    #pragma unroll
    for (int j = 0; j < 32; ++j) { v[j] = __expf(v[j] - m); s += v[j]; }
    #pragma unroll
    for (int off = 32; off > 0; off >>= 1) s += __shfl_xor(s, off);
    const float inv = 1.0f / s;

    #pragma unroll
    for (int c = 0; c < 4; ++c) {
        f16x8 y;
        #pragma unroll
        for (int j = 0; j < 8; ++j) y[j] = (f16)(v[c * 8 + j] * inv);
        *(f16x8*)&p[c * 8] = y;
    }
}

// ---------------------------------------------------------------------------
// fused fp32 -> f16 convert: blocks [0,3072) do x (6.29M elems),
// blocks [3072, 4224) do the 4 weight matrices (589824 elems each).
// ---------------------------------------------------------------------------
__global__ __launch_bounds__(256)
void cvt_all_kernel(const float* __restrict__ x,
                    const float* __restrict__ w0, const float* __restrict__ w1,
                    const float* __restrict__ w2, const float* __restrict__ w3,
                    f16* __restrict__ x16, f16* __restrict__ w16)
{
    const float* in; f16* out; long i;
    if (blockIdx.x < 3072) {
        in = x; out = x16;
        i = ((long)blockIdx.x * 256 + threadIdx.x) * 8;
    } else {
        const int wb  = blockIdx.x - 3072;          // 0..1151
        const int sel = wb / 288;                   // 288 blocks per weight
        in  = (sel == 0) ? w0 : (sel == 1) ? w1 : (sel == 2) ? w2 : w3;
        out = w16 + (long)sel * 589824;
        i = ((long)(wb - sel * 288) * 256 + threadIdx.x) * 8;
    }
    float4 a = *(const float4*)(in + i);
    float4 b = *(const float4*)(in + i + 4);
    f16x8 o;
    o[0] = (f16)a.x; o[1] = (f16)a.y; o[2] = (f16)a.z; o[3] = (f16)a.w;
    o[4] = (f16)b.x; o[5] = (f16)b.y; o[6] = (f16)b.z; o[7] = (f16)b.w;
    *(f16x8*)&out[i] = o;
}

// ---------------------------------------------------------------------------
// B=4, S=2048, D=H=768.  ws layout (bytes):
//   x16 @0  (12.6MB) | w16 @12582912 (4.7MB: wq,wk,wv,wo) | Q @17301504
//   K @29884416 | VT @42467328 ([4][768][2048]) | S @55050240 (33.5MB)
//   Y @88604672      total ~101 MB
// ---------------------------------------------------------------------------
extern "C" void kernel_launch(void* const* d_in, const int* in_sizes, int n_in,
                              void* d_out, int out_size, void* d_ws, size_t ws_size,
                              hipStream_t stream)
{
    const float* x  = (const float*)d_in[0];
    const float* wq = (const float*)d_in[1];
    const float* bq = (const float*)d_in[2];
    const float* wk = (const float*)d_in[3];
    const float* bk = (const float*)d_in[4];
    const float* wv = (const float*)d_in[5];
    const float* bv = (const float*)d_in[6];
    const float* wo = (const float*)d_in[7];
    const float* bo = (const float*)d_in[8];

    char* ws = (char*)d_ws;
    f16* x16 = (f16*)(ws + 0);
    f16* w16 = (f16*)(ws + 12582912);
    f16* Q   = (f16*)(ws + 17301504);
    f16* Kb  = (f16*)(ws + 29884416);
    f16* VT  = (f16*)(ws + 42467328);
    f16* S   = (f16*)(ws + 55050240);
    f16* Y   = (f16*)(ws + 88604672);

    f16* wv16 = w16 + 2 * 589824;
    f16* wo16 = w16 + 3 * 589824;

    cvt_all_kernel<<<4224, 256, 0, stream>>>(x, wq, wk, wv, wo, x16, w16);

    // fused Q|K projection: B = [wq;wk], N=1536, split outputs (768 blocks)
    gemm_kernel<f16, 128, 128, 3, 3><<<dim3(64, 12, 1), 256, 0, stream>>>(
        x16, 0, w16, 0, Q, 0, Kb, bq, bk, 1536, 768);
    // VT[b][h][s] = sum_d wv[h][d] x[b][s][d] + bv[h]  (row-bias, coalesced
    // row-major VT writes; 768 blocks)
    gemm_kernel<f16, 64, 128, 2, 4><<<dim3(12, 16, 4), 256, 0, stream>>>(
        wv16, 0, x16, (long)2048 * 768, VT, (long)768 * 2048, nullptr,
        bv, nullptr, 2048, 768);
    // S[b] = Q[b] @ K[b]^T  (128x256 tiles, 512 blocks — session best)
    gemm_kernel<f16, 128, 256, 0, 2><<<dim3(16, 8, 4), 256, 0, stream>>>(
        Q, (long)2048 * 768, Kb, (long)2048 * 768, S, (long)2048 * 2048,
        nullptr, nullptr, nullptr, 2048, 768);
    softmax_kernel<<<2048, 256, 0, stream>>>(S);
    // Y[b] = P[b] @ V[b]: A = S, B = VT  (128x64 tiles, 768 blocks, K=2048)
    gemm_kernel<f16, 128, 64, 0, 4><<<dim3(16, 12, 4), 256, 0, stream>>>(
        S, (long)2048 * 2048, VT, (long)768 * 2048, Y, (long)2048 * 768,
        nullptr, nullptr, nullptr, 768, 2048);
    // out = Y @ wo^T + bo (fp32 out, 128x64 tiles, 768 blocks)
    gemm_kernel<float, 128, 64, 1, 4><<<dim3(64, 12, 1), 256, 0, stream>>>(
        Y, 0, wo16, 0, (float*)d_out, 0, nullptr, bo, nullptr, 768, 768);
}